// Round 11
// baseline (151.940 us; speedup 1.0000x reference)
//
#include <hip/hip_runtime.h>
#include <hip/hip_bf16.h>

typedef __bf16 bf16x8 __attribute__((ext_vector_type(8)));
typedef float f32x4 __attribute__((ext_vector_type(4)));
typedef float f32x16 __attribute__((ext_vector_type(16)));
typedef unsigned short u16;
typedef unsigned int u32;

__device__ __forceinline__ u16 f2bf_rne(float f){
  union { float f; u32 u; } v; v.f = f;
  u32 r = v.u + 0x7fffu + ((v.u >> 16) & 1u);
  return (u16)(r >> 16);
}
// pack hi16(a)|hi16(b)<<16 in ONE v_perm_b32 (truncation; P feeds attention weights)
__device__ __forceinline__ u32 pack2(float a, float b){
  return __builtin_amdgcn_perm(__float_as_uint(a), __float_as_uint(b), 0x03020706u);
}
// workgroup barrier WITHOUT vmcnt drain (LDS visibility only): in-flight global
// loads (K/V register prefetches) ride through; compiler vmcnt-waits at use.
#define BARRIER_LGKM() asm volatile("s_waitcnt lgkmcnt(0)\n\ts_barrier" ::: "memory")

// ------------- prep: Wfrag = [Wh|Wf|Wg]^T in MFMA B-fragment order -------------
// Wfrag[cc(20)][kk(8)][lane(64)][j(8)] bf16; lane=(quad,L):
//   element = Wcat[k = kk*32 + quad*8 + j][n = cc*16 + L]
__global__ __launch_bounds__(512) void prep_kernel(
    const float* __restrict__ Wf, const float* __restrict__ Wg,
    const float* __restrict__ Wh, u16* __restrict__ Wfrag){
  const int cc = blockIdx.x;             // 20
  const int t = threadIdx.x;             // 512 = kk(8) x lane(64)
  const int kk = t >> 6, lane = t & 63;
  const int L = lane & 15, quad = lane >> 4;
  const int n = cc * 16 + L;
  u32 pk[4];
  #pragma unroll
  for (int j2 = 0; j2 < 4; ++j2){
    float v[2];
    #pragma unroll
    for (int h = 0; h < 2; ++h){
      int k = kk * 32 + quad * 8 + j2 * 2 + h;
      if (n < 256)      v[h] = Wh[k * 256 + n];
      else if (n < 288) v[h] = Wf[k * 32 + (n - 256)];
      else              v[h] = Wg[k * 32 + (n - 288)];
    }
    pk[j2] = (u32)f2bf_rne(v[0]) | ((u32)f2bf_rne(v[1]) << 16);
  }
  uint4* dst = (uint4*)(Wfrag + ((size_t)(cc * 8 + kk) * 64 + lane) * 8);
  *dst = make_uint4(pk[0], pk[1], pk[2], pk[3]);
}

// ---------------- projection: h/f/g via MFMA, 512 thr / 8 waves ----------------
// Qg pre-scaled by log2(e). V emitted fragment-major per 64-row group:
// Vfrag[g64][p_hi(8)][c(256)][j(8)], p = ((tn&15)<<2)|(tn>>4).
__global__ __launch_bounds__(512) void proj_kernel(
    const float* __restrict__ x, const u16* __restrict__ Wfrag,
    u16* __restrict__ Qg, u16* __restrict__ Kg, u16* __restrict__ Vfrag)
{
  __shared__ __align__(16) u16 smem[256 * 72];   // 36 KB, two phases
  u16 (*xb)[264] = (u16(*)[264])smem;
  u16 (*Vr)[72]  = (u16(*)[72])smem;

  const int tid = threadIdx.x;
  const int lane = tid & 63, wave = tid >> 6;
  const int L = lane & 15, quad = lane >> 4;
  const int rowgrp = wave >> 1, colhalf = wave & 1;
  const int n0 = blockIdx.x * 64;

  const float4* xsrc = (const float4*)(x + (size_t)n0 * 256);
  #pragma unroll
  for (int j = 0; j < 8; ++j){
    int idx = j * 512 + tid;
    int row = idx >> 6, col4 = idx & 63;
    float4 v = xsrc[idx];
    u32 p0 = (u32)f2bf_rne(v.x) | ((u32)f2bf_rne(v.y) << 16);
    u32 p1 = (u32)f2bf_rne(v.z) | ((u32)f2bf_rne(v.w) << 16);
    *(uint2*)&xb[row][col4 * 4] = make_uint2(p0, p1);
  }
  __syncthreads();

  f32x4 acc[10];
  #pragma unroll
  for (int cc = 0; cc < 10; ++cc) acc[cc] = (f32x4){0.f, 0.f, 0.f, 0.f};

  #pragma unroll
  for (int kk = 0; kk < 8; ++kk){
    bf16x8 a = *(const bf16x8*)&xb[rowgrp * 16 + L][kk * 32 + quad * 8];
    #pragma unroll
    for (int cc = 0; cc < 10; ++cc){
      int ccg = colhalf * 10 + cc;
      bf16x8 bfr = *(const bf16x8*)(Wfrag + ((size_t)(ccg * 8 + kk) * 64 + lane) * 8);
      acc[cc] = __builtin_amdgcn_mfma_f32_16x16x32_bf16(a, bfr, acc[cc], 0, 0, 0);
    }
  }

  if (colhalf){
    #pragma unroll
    for (int cc = 6; cc < 10; ++cc){
      int ccg = 10 + cc;                                  // 16..19
      u16* dst = (ccg < 18) ? Kg : Qg;                    // K = f, Q = g
      float sc = (ccg < 18) ? 1.0f : 1.44269504088896f;
      int c = (ccg & 1) * 16 + L;
      #pragma unroll
      for (int r = 0; r < 4; ++r){
        int row = n0 + rowgrp * 16 + quad * 4 + r;
        dst[(size_t)row * 32 + c] = f2bf_rne(acc[cc][r] * sc);
      }
    }
  }

  __syncthreads();   // xb consumed; reuse smem as Vr

  {
    const int cmax = colhalf ? 6 : 10;
    for (int cc = 0; cc < cmax; ++cc){
      int ccg = colhalf * 10 + cc;
      int c = ccg * 16 + L;
      #pragma unroll
      for (int r = 0; r < 4; ++r){
        int tn = rowgrp * 16 + quad * 4 + r;
        int p  = ((tn & 15) << 2) | (tn >> 4);
        Vr[c][p] = f2bf_rne(acc[cc][r]);
      }
    }
  }
  __syncthreads();

  u16* Vblk = Vfrag + (size_t)blockIdx.x * (256 * 64);
  #pragma unroll
  for (int i = 0; i < 4; ++i){
    int idx = i * 512 + tid;
    *(uint4*)(Vblk + (size_t)idx * 8) = *(const uint4*)&Vr[idx & 255][(idx >> 8) * 8];
  }
}

// ---- flash v11: producer-consumer, q-tile 128 x c-half 128, full-k ------------
// MODEL (R0-R10): flash is pinned at the per-CU L2->L1 DELIVERED-byte rate
// (~21-25 B/cyc/CU): R0 20.0, R3 24.1, R6 ~22, R10 21.1 B/cyc across five
// different schedules; chain-split (R10) bought only 5%. Only UNIQUE bytes per
// output help => amortize V over 2x q-rows. 256 blocks = b(4) x qt(32) x ch(2):
// each block: 128 q-rows, FULL k (softmax local per block; no combine), PV only
// for its own 128 V-cols. QK+softmax duplicated x2 across ch (producers ~700
// cyc/iter << mem term ~2000; R9's sin was x4 dup AND losing the MFMA pipe).
// Unique bytes/iter (2 k-tiles): V-half 32KB + K 16KB = 48KB vs R10's 80KB.
// Same skeleton as R10 (proven correct): waves 0-3 producers (each 32 q-rows:
// QK 16 mfma 16x16x32, exp2/pack, P store, K prefetch), waves 4-7 consumers
// (each 32 cols: PV 32 mfma 32x32x16 from Plds x V-regs, V prefetch).
// 1 barrier/iter; Plds [buf2][tile2][128][72] = 72KB, double-buffered: slab
// it&1 rewritten at it+2, one full lgkm-drained barrier after its last reads.
// ch-mates (ids differing by 8) share an XCD -> K/Q L2-local.
// Epilogue: consumers deposit O into Osh[128][128] (overlays Plds), producers
// reduce l -> Lsh[128]; single scale at coalesced out-write of the 128-col half.
__global__ __launch_bounds__(512) void flash_kernel(
    const u16* __restrict__ Qg, const u16* __restrict__ Kg, const u16* __restrict__ Vfrag,
    const float* __restrict__ x, const float* __restrict__ gamma, float* __restrict__ out)
{
  constexpr float SH = -92.33248261689366f;      // -64*log2(e); s already log2-scaled
  __shared__ __align__(16) char smem[73728];     // Plds 73728 B, Osh 64 KB overlay
  u16 (*Plds)[2][128][72] = (u16 (*)[2][128][72])smem;  // [buf][tile][row][72]
  float (*Osh)[128] = (float (*)[128])smem;             // [row][col] f32
  __shared__ float Lsh[128];

  const int tid = threadIdx.x, lane = tid & 63, wave = tid >> 6;
  const int L = lane & 15, quad = lane >> 4;
  const int m32 = lane & 31, h32 = lane >> 5;
  const bool producer = wave < 4;
  const int pw = wave & 3;                       // producer q-group / consumer c-group

  // id -> (b, qt, ch). id&7 = XCD; 2 XCDs per batch; ch-mates differ by bit3.
  const int id = blockIdx.x;                     // 0..255
  const int xcd = id & 7;
  const int b = xcd >> 1;
  const int ch = (id >> 3) & 1;
  const int qt = (xcd & 1) * 16 + (id >> 4);     // 0..31
  const int q0 = qt * 128;

  const u16* Qb = Qg + (size_t)(b * 4096) * 32;
  const u16* Kb = Kg + (size_t)(b * 4096) * 32;
  const u16* Vb = Vfrag + (size_t)b * (64 * 256 * 64);
  const float gm = gamma[0];

  const int ccol = ch * 128 + pw * 32 + m32;     // consumer's V/O column

  // ---- prologue ----
  bf16x8 qa0, qa1;
  bf16x8 kcA0, kcA1, kcA2, kcA3, kcB0, kcB1, kcB2, kcB3;
  bf16x8 vfA[4], vfB[4];
  if (producer){
    qa0 = *(const bf16x8*)(Qb + (size_t)(q0 + pw * 32 + L) * 32 + quad * 8);
    qa1 = *(const bf16x8*)(Qb + (size_t)(q0 + pw * 32 + 16 + L) * 32 + quad * 8);
    const u16* kpA = Kb + (size_t)(0 * 64 + L) * 32 + quad * 8;
    kcA0 = *(const bf16x8*)(kpA);
    kcA1 = *(const bf16x8*)(kpA + 512);
    kcA2 = *(const bf16x8*)(kpA + 1024);
    kcA3 = *(const bf16x8*)(kpA + 1536);
    const u16* kpB = kpA + 2048;
    kcB0 = *(const bf16x8*)(kpB);
    kcB1 = *(const bf16x8*)(kpB + 512);
    kcB2 = *(const bf16x8*)(kpB + 1024);
    kcB3 = *(const bf16x8*)(kpB + 1536);
  } else {
    #pragma unroll
    for (int ks = 0; ks < 4; ++ks){
      const u16* vrow = Vb + (size_t)((ks * 2 + h32) * 256 + ccol) * 8;
      vfA[ks] = *(const bf16x8*)(vrow);
      vfB[ks] = *(const bf16x8*)(vrow + 16384);  // tile stride = 8*256*8 u16
    }
  }

  f32x16 acc[4];                                  // consumers: [qi] = rows qi*32, own 32c
  #pragma unroll
  for (int t = 0; t < 4; ++t)
    #pragma unroll
    for (int i = 0; i < 16; ++i) acc[t][i] = 0.f;
  float lsum[2][4] = {{0.f,0.f,0.f,0.f},{0.f,0.f,0.f,0.f}};   // producers: [qg][r]
  const f32x4 zero = (f32x4){0.f, 0.f, 0.f, 0.f};

  for (int it = 0; it < 32; ++it){
    u16 (*PwA)[72] = Plds[it & 1][0];
    u16 (*PwB)[72] = Plds[it & 1][1];

    if (producer){
      // ---- QK^T for tiles 2it (A), 2it+1 (B), 32 q-rows; s log2-scaled ----
      f32x4 sA[2][4], sB[2][4];
      #pragma unroll
      for (int qg = 0; qg < 2; ++qg){
        bf16x8 q = qg ? qa1 : qa0;
        sA[qg][0] = __builtin_amdgcn_mfma_f32_16x16x32_bf16(q, kcA0, zero, 0, 0, 0);
        sA[qg][1] = __builtin_amdgcn_mfma_f32_16x16x32_bf16(q, kcA1, zero, 0, 0, 0);
        sA[qg][2] = __builtin_amdgcn_mfma_f32_16x16x32_bf16(q, kcA2, zero, 0, 0, 0);
        sA[qg][3] = __builtin_amdgcn_mfma_f32_16x16x32_bf16(q, kcA3, zero, 0, 0, 0);
        sB[qg][0] = __builtin_amdgcn_mfma_f32_16x16x32_bf16(q, kcB0, zero, 0, 0, 0);
        sB[qg][1] = __builtin_amdgcn_mfma_f32_16x16x32_bf16(q, kcB1, zero, 0, 0, 0);
        sB[qg][2] = __builtin_amdgcn_mfma_f32_16x16x32_bf16(q, kcB2, zero, 0, 0, 0);
        sB[qg][3] = __builtin_amdgcn_mfma_f32_16x16x32_bf16(q, kcB3, zero, 0, 0, 0);
      }

      // ---- K prefetch for it+1 (tiles 2it+2, 2it+3) ----
      if (it < 31){
        const u16* kpa = Kb + (size_t)((2 * it + 2) * 64 + L) * 32 + quad * 8;
        kcA0 = *(const bf16x8*)(kpa);
        kcA1 = *(const bf16x8*)(kpa + 512);
        kcA2 = *(const bf16x8*)(kpa + 1024);
        kcA3 = *(const bf16x8*)(kpa + 1536);
        const u16* kpb = kpa + 2048;
        kcB0 = *(const bf16x8*)(kpb);
        kcB1 = *(const bf16x8*)(kpb + 512);
        kcB2 = *(const bf16x8*)(kpb + 1024);
        kcB3 = *(const bf16x8*)(kpb + 1536);
      }

      // ---- p = exp2(s+SH); lsum; packed P stores, rows pw*32+qg*16+quad*4+r ----
      #pragma unroll
      for (int qg = 0; qg < 2; ++qg){
        #pragma unroll
        for (int r = 0; r < 4; ++r){
          float a0 = __builtin_amdgcn_exp2f(sA[qg][0][r] + SH);
          float a1 = __builtin_amdgcn_exp2f(sA[qg][1][r] + SH);
          float a2 = __builtin_amdgcn_exp2f(sA[qg][2][r] + SH);
          float a3 = __builtin_amdgcn_exp2f(sA[qg][3][r] + SH);
          float b0 = __builtin_amdgcn_exp2f(sB[qg][0][r] + SH);
          float b1 = __builtin_amdgcn_exp2f(sB[qg][1][r] + SH);
          float b2 = __builtin_amdgcn_exp2f(sB[qg][2][r] + SH);
          float b3 = __builtin_amdgcn_exp2f(sB[qg][3][r] + SH);
          lsum[qg][r] += ((a0 + a1) + (a2 + a3)) + ((b0 + b1) + (b2 + b3));
          int row = pw * 32 + qg * 16 + quad * 4 + r;
          *(uint2*)&PwA[row][L * 4] = make_uint2(pack2(a0, a1), pack2(a2, a3));
          *(uint2*)&PwB[row][L * 4] = make_uint2(pack2(b0, b1), pack2(b2, b3));
        }
      }
    }

    BARRIER_LGKM();   // P(it) visible; K/V register prefetches ride through

    if (!producer){
      // ---- O += P(A) V(A) + P(B) V(B): af from Plds (4 q-blocks), vf in regs ----
      #pragma unroll
      for (int qi = 0; qi < 4; ++qi){
        #pragma unroll
        for (int ks = 0; ks < 4; ++ks){
          bf16x8 af = *(const bf16x8*)&PwA[qi * 32 + m32][ks * 16 + h32 * 8];
          acc[qi] = __builtin_amdgcn_mfma_f32_32x32x16_bf16(af, vfA[ks], acc[qi], 0, 0, 0);
        }
        #pragma unroll
        for (int ks = 0; ks < 4; ++ks){
          bf16x8 af = *(const bf16x8*)&PwB[qi * 32 + m32][ks * 16 + h32 * 8];
          acc[qi] = __builtin_amdgcn_mfma_f32_32x32x16_bf16(af, vfB[ks], acc[qi], 0, 0, 0);
        }
      }
      // ---- V prefetch for it+1 (tiles 2it+2, 2it+3), own 32-col slice ----
      if (it < 31){
        const u16* Vn = Vb + (size_t)(2 * it + 2) * (256 * 64);
        #pragma unroll
        for (int ks = 0; ks < 4; ++ks){
          const u16* vrow = Vn + (size_t)((ks * 2 + h32) * 256 + ccol) * 8;
          vfA[ks] = *(const bf16x8*)(vrow);
          vfB[ks] = *(const bf16x8*)(vrow + 16384);
        }
      }
    }
    // no end barrier: 2-deep P slabs; rewrite gated by next barrier (see header)
  }

  // ================= epilogue =================
  BARRIER_LGKM();   // all PV ds-reads retired; Plds region reusable as Osh

  if (producer){
    // l over full k: reduce the 16 L-partials per (qg,quad,r)
    #pragma unroll
    for (int qg = 0; qg < 2; ++qg){
      #pragma unroll
      for (int r = 0; r < 4; ++r){
        float v = lsum[qg][r];
        v += __shfl_xor(v, 1);
        v += __shfl_xor(v, 2);
        v += __shfl_xor(v, 4);
        v += __shfl_xor(v, 8);
        if (L == 0) Lsh[pw * 32 + qg * 16 + quad * 4 + r] = v;
      }
    }
  } else {
    // consumers deposit O (4 q-blocks x own 32 cols) into Osh
    #pragma unroll
    for (int qi = 0; qi < 4; ++qi){
      #pragma unroll
      for (int rg = 0; rg < 16; ++rg){
        int crow = (rg & 3) + 8 * (rg >> 2) + 4 * h32;   // 32x32 C-layout
        Osh[qi * 32 + crow][pw * 32 + m32] = acc[qi][rg];
      }
    }
  }
  __syncthreads();
  if (tid < 128) Lsh[tid] = gm / Lsh[tid];       // per-row scale factor
  __syncthreads();
  // coalesced: out = Osh * (gamma/l) + x over rows [q0,+128) x cols [ch*128,+128)
  const size_t base = ((size_t)(b * 4096 + q0)) * 256 + ch * 128;
  #pragma unroll
  for (int i = 0; i < 8; ++i){
    int idx = i * 512 + tid;                     // 0..4095 float4s
    int row = idx >> 5, c4 = idx & 31;
    size_t off = base + (size_t)row * 256 + c4 * 4;
    float li = Lsh[row];
    float4 o = *(const float4*)&Osh[row][c4 * 4];
    float4 xv = *(const float4*)(x + off);
    o.x = o.x * li + xv.x; o.y = o.y * li + xv.y;
    o.z = o.z * li + xv.z; o.w = o.w * li + xv.w;
    *(float4*)(out + off) = o;
  }
}

extern "C" void kernel_launch(void* const* d_in, const int* in_sizes, int n_in,
                              void* d_out, int out_size, void* d_ws, size_t ws_size,
                              hipStream_t stream) {
  const float* x     = (const float*)d_in[0];
  const float* Wf    = (const float*)d_in[1];
  const float* Wg    = (const float*)d_in[2];
  const float* Wh    = (const float*)d_in[3];
  const float* gamma = (const float*)d_in[4];
  float* out = (float*)d_out;

  u16* p = (u16*)d_ws;
  u16* Qg    = p;  p += 16384 * 32;               // 1 MB
  u16* Kg    = p;  p += 16384 * 32;               // 1 MB
  u16* Vfrag = p;  p += 4 * 64 * 256 * 64;        // 8 MB, fragment-major
  u16* Wfrag = p;  p += 20 * 8 * 64 * 8;          // 160 KB, fragment-major

  prep_kernel<<<20, 512, 0, stream>>>(Wf, Wg, Wh, Wfrag);
  proj_kernel<<<256, 512, 0, stream>>>(x, Wfrag, Qg, Kg, Vfrag);
  flash_kernel<<<256, 512, 0, stream>>>(Qg, Kg, Vfrag, x, gamma, out);
}